// Round 6
// baseline (110.708 us; speedup 1.0000x reference)
//
#include <hip/hip_runtime.h>
#include <stdint.h>

// Fused softmax + top-8 (renormalized) over 64 experts.
// Layout: 1 wave = 8 tokens; 8 lanes per token; 8 logits per lane.
// Keys: u64 (monotonic_u32(logit) << 6) | (63 - expert_idx)
//   -> exact ordering, ties -> lower expert index (jax.lax.top_k stable).
// All CEs use full-rate 32-bit ops (v_cmp_lt_u64 + cndmask), no f64 pipe.
// Selection: per-lane sort-8 + 3-level symmetric bitonic merge via DPP.

typedef float f32x4 __attribute__((ext_vector_type(4)));

#define DPP_QUAD_XOR1   0xB1   // quad_perm(1,0,3,2)  : lane ^ 1
#define DPP_QUAD_XOR2   0x4E   // quad_perm(2,3,0,1)  : lane ^ 2
#define DPP_HALF_MIRROR 0x141  // row_half_mirror     : lane <-> 7-lane (in 8)

template<int CTRL>
static __device__ __forceinline__ uint64_t dpp64(uint64_t x) {
    int lo = __builtin_amdgcn_update_dpp(0, (int)(uint32_t)x,         CTRL, 0xF, 0xF, true);
    int hi = __builtin_amdgcn_update_dpp(0, (int)(uint32_t)(x >> 32), CTRL, 0xF, 0xF, true);
    return ((uint64_t)(uint32_t)hi << 32) | (uint32_t)lo;
}

template<int CTRL>
static __device__ __forceinline__ float dppf(float x) {
    int i = __builtin_amdgcn_update_dpp(0, __float_as_int(x), CTRL, 0xF, 0xF, true);
    return __int_as_float(i);
}

// compare-exchange, descending (max to x): v_cmp_lt_u64 + 4x v_cndmask_b32
#define CEU(x, y) { uint64_t a_ = x, b_ = y; bool c_ = a_ < b_; \
                    x = c_ ? b_ : a_; y = c_ ? a_ : b_; }

template<int CTRL>
static __device__ __forceinline__ void merge_level(uint64_t k[8]) {
    // m[i] = max(own[i], partner[7-i]) -> top-8 of union (bitonic), then clean.
    uint64_t m[8];
#pragma unroll
    for (int i = 0; i < 8; ++i) {
        uint64_t p = dpp64<CTRL>(k[7 - i]);
        m[i] = (k[i] > p) ? k[i] : p;      // keys unique -> no tie ambiguity
    }
    CEU(m[0], m[4]) CEU(m[1], m[5]) CEU(m[2], m[6]) CEU(m[3], m[7])
    CEU(m[0], m[2]) CEU(m[1], m[3]) CEU(m[4], m[6]) CEU(m[5], m[7])
    CEU(m[0], m[1]) CEU(m[2], m[3]) CEU(m[4], m[5]) CEU(m[6], m[7])
#pragma unroll
    for (int i = 0; i < 8; ++i) k[i] = m[i];
}

static __device__ __forceinline__ uint32_t mono(float v) {
    uint32_t u = __float_as_uint(v);
    return u ^ (uint32_t)(((int32_t)u >> 31) | 0x80000000);   // ascending map
}

__global__ __launch_bounds__(256) void topk_softmax_k(
    const float* __restrict__ logits,
    float* __restrict__ out_w,
    float* __restrict__ out_id,
    float* __restrict__ out_tei,
    int T)
{
    const int  lane = threadIdx.x & 63;
    const int  wv   = (int)(threadIdx.x >> 6);
    const long t0   = (long)blockIdx.x * 32 + (long)wv * 8;   // first token of wave
    if (t0 >= T) return;

    const int  sub = lane & 7;
    const bool act = (t0 + (lane >> 3)) < T;

    // lane l reads logits[t0*64 + l*8 .. +7] -> wave covers 2KiB contiguous
    const f32x4* src = reinterpret_cast<const f32x4*>(logits)
                     + (act ? (t0 * 16 + (long)lane * 2) : 0);
    f32x4 a = __builtin_nontemporal_load(src);
    f32x4 b = __builtin_nontemporal_load(src + 1);

    const uint32_t cb = (uint32_t)(63 - sub * 8);  // 6-bit tiebreak, hi = low idx
    uint64_t k[8];
    k[0] = ((uint64_t)mono(a.x) << 6) | (cb    );
    k[1] = ((uint64_t)mono(a.y) << 6) | (cb - 1);
    k[2] = ((uint64_t)mono(a.z) << 6) | (cb - 2);
    k[3] = ((uint64_t)mono(a.w) << 6) | (cb - 3);
    k[4] = ((uint64_t)mono(b.x) << 6) | (cb - 4);
    k[5] = ((uint64_t)mono(b.y) << 6) | (cb - 5);
    k[6] = ((uint64_t)mono(b.z) << 6) | (cb - 6);
    k[7] = ((uint64_t)mono(b.w) << 6) | (cb - 7);

    // sort lane's 8 keys descending (Batcher odd-even merge, 19 CE)
    CEU(k[0],k[1]) CEU(k[2],k[3]) CEU(k[4],k[5]) CEU(k[6],k[7])
    CEU(k[0],k[2]) CEU(k[1],k[3]) CEU(k[4],k[6]) CEU(k[5],k[7])
    CEU(k[1],k[2]) CEU(k[5],k[6])
    CEU(k[0],k[4]) CEU(k[1],k[5]) CEU(k[2],k[6]) CEU(k[3],k[7])
    CEU(k[2],k[4]) CEU(k[3],k[5])
    CEU(k[1],k[2]) CEU(k[3],k[4]) CEU(k[5],k[6])

    // 3-level symmetric merge: all 8 lanes end with global top-8 sorted desc.
    merge_level<DPP_QUAD_XOR1>(k);
    merge_level<DPP_QUAD_XOR2>(k);
    merge_level<DPP_HALF_MIRROR>(k);

    // lane `sub` takes slot `sub` (static-index select tree, cndmask pairs)
    uint64_t t4a = (sub & 4) ? k[4] : k[0];
    uint64_t t4b = (sub & 4) ? k[5] : k[1];
    uint64_t t4c = (sub & 4) ? k[6] : k[2];
    uint64_t t4d = (sub & 4) ? k[7] : k[3];
    uint64_t t2a = (sub & 2) ? t4c : t4a;
    uint64_t t2b = (sub & 2) ? t4d : t4b;
    uint64_t sel = (sub & 1) ? t2b : t2a;

    // decode max (slot 0) value
    uint32_t o0 = (uint32_t)(k[0] >> 6);
    uint32_t mb = (o0 & 0x80000000u) ? (o0 ^ 0x80000000u) : ~o0;
    float    mv = __uint_as_float(mb);

    // decode own slot (value, index)
    uint32_t os  = (uint32_t)(sel >> 6);
    uint32_t ub  = (os & 0x80000000u) ? (os ^ 0x80000000u) : ~os;
    float    v   = __uint_as_float(ub);
    int      idx = 63 - (int)((uint32_t)sel & 63u);

    // renormalized weight = exp(v - max) / sum_top8 exp(. - max)
    float e = __expf(v - mv);
    float s = e;
    s += dppf<DPP_QUAD_XOR1>(s);
    s += dppf<DPP_QUAD_XOR2>(s);
    s += dppf<DPP_HALF_MIRROR>(s);
    float wgt = e * __builtin_amdgcn_rcpf(s);

    if (act) {
        const long oi = t0 * 8 + lane;           // == token*8 + sub
        __builtin_nontemporal_store(wgt,        &out_w[oi]);
        __builtin_nontemporal_store((float)idx, &out_id[oi]);
        __builtin_nontemporal_store((float)oi,  &out_tei[oi]);
    }
}

extern "C" void kernel_launch(void* const* d_in, const int* in_sizes, int n_in,
                              void* d_out, int out_size, void* d_ws, size_t ws_size,
                              hipStream_t stream) {
    const float* logits = (const float*)d_in[0];
    const int T = in_sizes[0] / 64;

    float* outw = (float*)d_out;
    float* outi = outw + (size_t)T * 8;
    float* outt = outi + (size_t)T * 8;

    const int blocks = (T + 31) / 32;   // 32 tokens per 256-thread block
    hipLaunchKernelGGL(topk_softmax_k, dim3(blocks), dim3(256), 0, stream,
                       logits, outw, outi, outt, T);
}

// Round 7
// 87.389 us; speedup vs baseline: 1.2668x; 1.2668x over previous
//
#include <hip/hip_runtime.h>
#include <stdint.h>

// Fused softmax + top-8 (renormalized) over 64 experts.
// Layout: 1 wave = 8 tokens; 8 lanes per token; 8 logits per lane.
// Fast path: value-only u32 network (v_max_u32/v_min_u32, full rate, no vcc),
//   then exact index recovery via rank-binsearch + byte-OR delivery.
//   Tie cases (dup value among qualified set) are DETECTED exactly
//   (qualified-count != 8 or empty output byte) and fall back per-group to
//   the R3 u64-key serial extraction (exact jax.lax.top_k tie-break).

typedef float f32x4 __attribute__((ext_vector_type(4)));

#define DPP_QUAD_XOR1   0xB1   // quad_perm(1,0,3,2)  : lane ^ 1
#define DPP_QUAD_XOR2   0x4E   // quad_perm(2,3,0,1)  : lane ^ 2
#define DPP_HALF_MIRROR 0x141  // row_half_mirror     : lane <-> 7-lane (in 8)

template<int CTRL>
static __device__ __forceinline__ uint32_t dpp32(uint32_t x) {
    return (uint32_t)__builtin_amdgcn_update_dpp(0, (int)x, CTRL, 0xF, 0xF, true);
}
template<int CTRL>
static __device__ __forceinline__ uint64_t dpp64(uint64_t x) {
    int lo = __builtin_amdgcn_update_dpp(0, (int)(uint32_t)x,         CTRL, 0xF, 0xF, true);
    int hi = __builtin_amdgcn_update_dpp(0, (int)(uint32_t)(x >> 32), CTRL, 0xF, 0xF, true);
    return ((uint64_t)(uint32_t)hi << 32) | (uint32_t)lo;
}
template<int CTRL>
static __device__ __forceinline__ float dppf(float x) {
    int i = __builtin_amdgcn_update_dpp(0, __float_as_int(x), CTRL, 0xF, 0xF, true);
    return __int_as_float(i);
}

// compare-exchange desc on u32: v_max_u32 + v_min_u32 (no vcc dependency)
#define CE32(x, y) { uint32_t gt_ = (x > y) ? x : y; uint32_t lt_ = (x > y) ? y : x; \
                     x = gt_; y = lt_; }
// u64 CE (slow path only)
#define CEU(x, y) { uint64_t a_ = x, b_ = y; bool c_ = a_ < b_; \
                    x = c_ ? b_ : a_; y = c_ ? a_ : b_; }

template<int CTRL>
static __device__ __forceinline__ void merge_u32(uint32_t k[8]) {
    // m[i] = max(own[i], partner[7-i]) -> top-8 of union (bitonic), then clean.
    uint32_t m[8];
#pragma unroll
    for (int i = 0; i < 8; ++i) {
        uint32_t p = dpp32<CTRL>(k[7 - i]);
        m[i] = (k[i] > p) ? k[i] : p;
    }
    CE32(m[0], m[4]) CE32(m[1], m[5]) CE32(m[2], m[6]) CE32(m[3], m[7])
    CE32(m[0], m[2]) CE32(m[1], m[3]) CE32(m[4], m[6]) CE32(m[5], m[7])
    CE32(m[0], m[1]) CE32(m[2], m[3]) CE32(m[4], m[5]) CE32(m[6], m[7])
#pragma unroll
    for (int i = 0; i < 8; ++i) k[i] = m[i];
}

static __device__ __forceinline__ uint32_t mono(float v) {
    uint32_t u = __float_as_uint(v);
    return u ^ (uint32_t)(((int32_t)u >> 31) | 0x80000000);   // ascending map
}
static __device__ __forceinline__ float unmono(uint32_t m) {
    uint32_t u = (m & 0x80000000u) ? (m ^ 0x80000000u) : ~m;
    return __uint_as_float(u);
}

__global__ __launch_bounds__(256) void topk_softmax_k(
    const float* __restrict__ logits,
    float* __restrict__ out_w,
    float* __restrict__ out_id,
    float* __restrict__ out_tei,
    int T)
{
    const int  lane = threadIdx.x & 63;
    const int  wv   = (int)(threadIdx.x >> 6);
    const long t0   = (long)blockIdx.x * 32 + (long)wv * 8;   // first token of wave
    if (t0 >= T) return;

    const int  sub = lane & 7;
    const bool act = (t0 + (lane >> 3)) < T;

    // lane l reads logits[t0*64 + l*8 .. +7] -> wave covers 2KiB contiguous
    const f32x4* src = reinterpret_cast<const f32x4*>(logits)
                     + (act ? (t0 * 16 + (long)lane * 2) : 0);
    f32x4 a = __builtin_nontemporal_load(src);
    f32x4 b = __builtin_nontemporal_load(src + 1);

    // originals (ascending-mapped); expert id of o[j] is sub*8 + j
    uint32_t o[8] = { mono(a.x), mono(a.y), mono(a.z), mono(a.w),
                      mono(b.x), mono(b.y), mono(b.z), mono(b.w) };

    // ---- value-only network: sort-8 desc + 3-level symmetric merge ----
    uint32_t k[8];
#pragma unroll
    for (int j = 0; j < 8; ++j) k[j] = o[j];

    CE32(k[0],k[1]) CE32(k[2],k[3]) CE32(k[4],k[5]) CE32(k[6],k[7])
    CE32(k[0],k[2]) CE32(k[1],k[3]) CE32(k[4],k[6]) CE32(k[5],k[7])
    CE32(k[1],k[2]) CE32(k[5],k[6])
    CE32(k[0],k[4]) CE32(k[1],k[5]) CE32(k[2],k[6]) CE32(k[3],k[7])
    CE32(k[2],k[4]) CE32(k[3],k[5])
    CE32(k[1],k[2]) CE32(k[3],k[4]) CE32(k[5],k[6])

    merge_u32<DPP_QUAD_XOR1>(k);
    merge_u32<DPP_QUAD_XOR2>(k);
    merge_u32<DPP_HALF_MIRROR>(k);
    // now every lane holds the token's top-8 VALUES sorted desc in k[0..7]

    // ---- rank each original, deliver expert+1 into byte[rank] of acc ----
    const uint32_t m7 = k[7];
    uint64_t acc  = 0;
    uint32_t qcnt = 0;
#pragma unroll
    for (int j = 0; j < 8; ++j) {
        uint32_t oj = o[j];
        uint32_t q  = (oj >= m7) ? 1u : 0u;
        // rank = #{s : k[s] > oj} via 3-probe select-tree binary search
        bool     b2 = (k[3] > oj);
        uint32_t p1 = b2 ? k[5] : k[1];
        bool     b1 = (p1 > oj);
        uint32_t p0 = b1 ? (b2 ? k[6] : k[2]) : (b2 ? k[4] : k[0]);
        bool     b0 = (p0 > oj);
        uint32_t sh = (b2 ? 32u : 0u) + (b1 ? 16u : 0u) + (b0 ? 8u : 0u);
        uint32_t payload = q ? (uint32_t)(sub * 8 + j + 1) : 0u;
        acc  |= (uint64_t)payload << sh;
        qcnt += q;
    }
    // group reduces (8-lane group)
    acc |= dpp64<DPP_QUAD_XOR1>(acc);
    acc |= dpp64<DPP_QUAD_XOR2>(acc);
    acc |= dpp64<DPP_HALF_MIRROR>(acc);
    qcnt += dpp32<DPP_QUAD_XOR1>(qcnt);
    qcnt += dpp32<DPP_QUAD_XOR2>(qcnt);
    qcnt += dpp32<DPP_HALF_MIRROR>(qcnt);

    uint32_t mybyte = (uint32_t)(acc >> (sub * 8)) & 0xFFu;
    uint32_t zf = (mybyte == 0) ? 1u : 0u;
    zf |= dpp32<DPP_QUAD_XOR1>(zf);
    zf |= dpp32<DPP_QUAD_XOR2>(zf);
    zf |= dpp32<DPP_HALF_MIRROR>(zf);

    const bool bad = (qcnt != 8u) || (zf != 0u);   // group-uniform

    uint32_t selmono, maxmono;
    int idx;
    if (!bad) {
        // fast: value at slot sub via static select tree; index from byte
        uint32_t t4a = (sub & 4) ? k[4] : k[0];
        uint32_t t4b = (sub & 4) ? k[5] : k[1];
        uint32_t t4c = (sub & 4) ? k[6] : k[2];
        uint32_t t4d = (sub & 4) ? k[7] : k[3];
        uint32_t t2a = (sub & 2) ? t4c : t4a;
        uint32_t t2b = (sub & 2) ? t4d : t4b;
        selmono = (sub & 1) ? t2b : t2a;
        maxmono = k[0];
        idx = (int)mybyte - 1;
    } else {
        // slow (rare, exact): R3 u64-key serial extraction, stable tie-break
        const uint32_t cb = (uint32_t)(63 - sub * 8);
        uint64_t kk[8];
#pragma unroll
        for (int j = 0; j < 8; ++j)
            kk[j] = ((uint64_t)o[j] << 6) | (uint64_t)(cb - (uint32_t)j);

        CEU(kk[0],kk[1]) CEU(kk[2],kk[3]) CEU(kk[4],kk[5]) CEU(kk[6],kk[7])
        CEU(kk[0],kk[2]) CEU(kk[1],kk[3]) CEU(kk[4],kk[6]) CEU(kk[5],kk[7])
        CEU(kk[1],kk[2]) CEU(kk[5],kk[6])
        CEU(kk[0],kk[4]) CEU(kk[1],kk[5]) CEU(kk[2],kk[6]) CEU(kk[3],kk[7])
        CEU(kk[2],kk[4]) CEU(kk[3],kk[5])
        CEU(kk[1],kk[2]) CEU(kk[3],kk[4]) CEU(kk[5],kk[6])

        uint64_t mykey = 0, mtop = 0;
#pragma unroll
        for (int r = 0; r < 8; ++r) {
            uint64_t w = kk[0];
            { uint64_t t = dpp64<DPP_QUAD_XOR1>(w);   if (t > w) w = t; }
            { uint64_t t = dpp64<DPP_QUAD_XOR2>(w);   if (t > w) w = t; }
            { uint64_t t = dpp64<DPP_HALF_MIRROR>(w); if (t > w) w = t; }
            if (r == 0)   mtop  = w;
            if (sub == r) mykey = w;
            bool pop = (kk[0] == w);   // unique keys -> one lane pops
            kk[0] = pop ? kk[1] : kk[0];
            kk[1] = pop ? kk[2] : kk[1];
            kk[2] = pop ? kk[3] : kk[2];
            kk[3] = pop ? kk[4] : kk[3];
            kk[4] = pop ? kk[5] : kk[4];
            kk[5] = pop ? kk[6] : kk[5];
            kk[6] = pop ? kk[7] : kk[6];
            kk[7] = pop ? 0     : kk[7];
        }
        selmono = (uint32_t)(mykey >> 6);
        maxmono = (uint32_t)(mtop  >> 6);
        idx = 63 - (int)((uint32_t)mykey & 63u);
    }

    const float v  = unmono(selmono);
    const float mv = unmono(maxmono);

    // renormalized weight = exp(v - max) / sum_top8 exp(. - max)
    float e = __expf(v - mv);
    float s = e;
    s += dppf<DPP_QUAD_XOR1>(s);
    s += dppf<DPP_QUAD_XOR2>(s);
    s += dppf<DPP_HALF_MIRROR>(s);
    float wgt = e * __builtin_amdgcn_rcpf(s);

    if (act) {
        const long oi = t0 * 8 + lane;           // == token*8 + sub
        __builtin_nontemporal_store(wgt,        &out_w[oi]);
        __builtin_nontemporal_store((float)idx, &out_id[oi]);
        __builtin_nontemporal_store((float)oi,  &out_tei[oi]);
    }
}

extern "C" void kernel_launch(void* const* d_in, const int* in_sizes, int n_in,
                              void* d_out, int out_size, void* d_ws, size_t ws_size,
                              hipStream_t stream) {
    const float* logits = (const float*)d_in[0];
    const int T = in_sizes[0] / 64;

    float* outw = (float*)d_out;
    float* outi = outw + (size_t)T * 8;
    float* outt = outi + (size_t)T * 8;

    const int blocks = (T + 31) / 32;   // 32 tokens per 256-thread block
    hipLaunchKernelGGL(topk_softmax_k, dim3(blocks), dim3(256), 0, stream,
                       logits, outw, outi, outt, T);
}